// Round 1
// baseline (212.255 us; speedup 1.0000x reference)
//
#include <hip/hip_runtime.h>
#include <math.h>

// NeRF ray integration: one 64-lane wave per ray, 2 samples/lane (S=128).
// wi[s] = exp(-excl_cumsum(sigma*dt)[s]) - exp(-incl_cumsum(sigma*dt)[s])
// dt[s] = t[s+1]-t[s], dt[S-1] = 0 (infinite=False). Output t == input t
// (input is pre-sorted; reference's sort is a no-op).

#define NRAYS 65536
#define S 128
#define RAYS_PER_BLOCK 4

__global__ __launch_bounds__(256) void nerf_render_kernel(
    const float* __restrict__ t,
    const float* __restrict__ sigma,
    const float* __restrict__ color,
    float* __restrict__ out_color,   // [N,3]
    float* __restrict__ out_depth,   // [N,1]
    float* __restrict__ out_wi,      // [N,S]
    float* __restrict__ out_t)       // [N,S]
{
    const int wave = threadIdx.x >> 6;
    const int lane = threadIdx.x & 63;
    const int ray  = blockIdx.x * RAYS_PER_BLOCK + wave;

    const long sbase = (long)ray * S + 2 * lane;     // sample index of first of pair

    // --- loads (coalesced, 8B/lane for t & sigma, 24B/lane for color) ---
    const float2 tv = *(const float2*)(t + sbase);
    const float2 sv = *(const float2*)(sigma + sbase);
    const float2* cp = (const float2*)(color + (long)ray * (S * 3) + 6 * lane);
    const float2 c01 = cp[0];   // r0 g0
    const float2 c23 = cp[1];   // b0 r1
    const float2 c45 = cp[2];   // g1 b1

    // --- dt stencil: need next lane's t.x for dt of second sample ---
    const float t_next = __shfl_down(tv.x, 1, 64);   // t[2*lane+2]
    const float dt0 = tv.y - tv.x;
    const float dt1 = (lane == 63) ? 0.0f : (t_next - tv.y);

    const float sdt0 = sv.x * dt0;
    const float sdt1 = sv.y * dt1;
    const float pairsum = sdt0 + sdt1;

    // --- wave-inclusive scan of pair sums (6 shfl_up steps) ---
    float scan = pairsum;
    #pragma unroll
    for (int off = 1; off < 64; off <<= 1) {
        const float v = __shfl_up(scan, off, 64);
        if (lane >= off) scan += v;
    }
    const float excl  = scan - pairsum;      // cumsum before sample 2*lane
    const float mid   = excl + sdt0;         // cumsum incl sample 2*lane

    const float E0 = expf(-excl);
    const float E1 = expf(-mid);
    const float E2 = expf(-scan);
    const float wi0 = E0 - E1;
    const float wi1 = E1 - E2;

    // --- streamed outputs ---
    *(float2*)(out_wi + sbase) = make_float2(wi0, wi1);
    *(float2*)(out_t  + sbase) = tv;

    // --- per-ray reductions: rgb + depth ---
    float r = wi0 * c01.x + wi1 * c23.y;
    float g = wi0 * c01.y + wi1 * c45.x;
    float b = wi0 * c23.x + wi1 * c45.y;
    float d = wi0 * tv.x  + wi1 * tv.y;

    #pragma unroll
    for (int off = 32; off >= 1; off >>= 1) {
        r += __shfl_xor(r, off, 64);
        g += __shfl_xor(g, off, 64);
        b += __shfl_xor(b, off, 64);
        d += __shfl_xor(d, off, 64);
    }

    if (lane == 0) {
        out_color[(long)ray * 3 + 0] = r;
        out_color[(long)ray * 3 + 1] = g;
        out_color[(long)ray * 3 + 2] = b;
        out_depth[ray] = d;
    }
}

extern "C" void kernel_launch(void* const* d_in, const int* in_sizes, int n_in,
                              void* d_out, int out_size, void* d_ws, size_t ws_size,
                              hipStream_t stream) {
    const float* t     = (const float*)d_in[0];
    const float* sigma = (const float*)d_in[1];
    const float* color = (const float*)d_in[2];

    float* out = (float*)d_out;
    float* out_color = out;                        // N*3
    float* out_depth = out_color + (long)NRAYS * 3; // N
    float* out_wi    = out_depth + NRAYS;           // N*S
    float* out_t     = out_wi + (long)NRAYS * S;    // N*S

    const int blocks = NRAYS / RAYS_PER_BLOCK;     // 16384
    nerf_render_kernel<<<blocks, 256, 0, stream>>>(
        t, sigma, color, out_color, out_depth, out_wi, out_t);
}